// Round 1
// baseline (916.977 us; speedup 1.0000x reference)
//
#include <hip/hip_runtime.h>
#include <hip/hip_bf16.h>

#define NN 30000
#define EE 480000
#define C  128

static __device__ __forceinline__ unsigned short f2bf_rn(float f) {
    unsigned int u = __float_as_uint(f);
    unsigned int r = (u + 0x7fffu + ((u >> 16) & 1u)) >> 16;
    return (unsigned short)r;
}
static __device__ __forceinline__ float bf2f(unsigned short s) {
    return __uint_as_float(((unsigned int)s) << 16);
}

// ---------------- K1: node GEMMs (q,k,v -> ws, root -> out) ----------------
__global__ __launch_bounds__(256) void node_gemm(
    const float* __restrict__ x,
    const float* __restrict__ Wq, const float* __restrict__ Wk,
    const float* __restrict__ Wv, const float* __restrict__ Wr,
    const float* __restrict__ root_b,
    float* __restrict__ q, float* __restrict__ k, float* __restrict__ v,
    float* __restrict__ out)
{
    const int m = blockIdx.y;
    const float* W = (m == 0) ? Wq : (m == 1) ? Wk : (m == 2) ? Wv : Wr;
    float* O = (m == 0) ? q : (m == 1) ? k : (m == 2) ? v : out;

    const int n0 = blockIdx.x * 32;
    const int t  = threadIdx.x;
    __shared__ float sx[32][C];

    for (int idx = t; idx < 32 * C; idx += 256) {
        int i = idx >> 7, c = idx & 127;
        int n = n0 + i;
        sx[i][c] = (n < NN) ? x[(size_t)n * C + c] : 0.0f;
    }
    __syncthreads();

    const int jc = (t & 31) * 4;
    const int er = (t >> 5) * 4;
    float acc[4][4] = {};

    for (int kk = 0; kk < C; ++kk) {
        float4 b = *(const float4*)(W + kk * C + jc);
        #pragma unroll
        for (int i = 0; i < 4; ++i) {
            float a = sx[er + i][kk];
            acc[i][0] = fmaf(a, b.x, acc[i][0]);
            acc[i][1] = fmaf(a, b.y, acc[i][1]);
            acc[i][2] = fmaf(a, b.z, acc[i][2]);
            acc[i][3] = fmaf(a, b.w, acc[i][3]);
        }
    }

    float4 bias = make_float4(0.f, 0.f, 0.f, 0.f);
    if (m == 3) bias = *(const float4*)(root_b + jc);

    #pragma unroll
    for (int i = 0; i < 4; ++i) {
        int n = n0 + er + i;
        if (n < NN) {
            float4 r;
            r.x = acc[i][0] + bias.x;
            r.y = acc[i][1] + bias.y;
            r.z = acc[i][2] + bias.z;
            r.w = acc[i][3] + bias.w;
            *(float4*)(O + (size_t)n * C + jc) = r;
        }
    }
}

// ---------------- K2: per-edge fused MLPs -> delta(bf16), logits ----------------
__global__ __launch_bounds__(256) void edge_kernel(
    const float* __restrict__ pos, const int* __restrict__ eidx,
    const float* __restrict__ q, const float* __restrict__ k,
    const float* __restrict__ pm_w1, const float* __restrict__ pm_b1,
    const float* __restrict__ pm_w2, const float* __restrict__ pm_b2,
    const float* __restrict__ at_w1, const float* __restrict__ at_b1,
    const float* __restrict__ at_w2, const float* __restrict__ at_b2,
    unsigned short* __restrict__ dbf, float* __restrict__ logits)
{
    const int e0 = blockIdx.x * 32;
    const int t  = threadIdx.x;

    __shared__ float s_a[32][C];   // t1, then h
    __shared__ float s_b[32][C];   // t2
    __shared__ int   s_row[32], s_col[32];
    __shared__ float s_dp[32][3];

    if (t < 32) {
        int e = e0 + t;
        int r = eidx[e], c = eidx[EE + e];
        s_row[t] = r; s_col[t] = c;
        s_dp[t][0] = pos[r * 3 + 0] - pos[c * 3 + 0];
        s_dp[t][1] = pos[r * 3 + 1] - pos[c * 3 + 1];
        s_dp[t][2] = pos[r * 3 + 2] - pos[c * 3 + 2];
    }
    __syncthreads();

    // phase 1: t1 = relu(dpos @ pm_w1 + b1)
    {
        int j = t & 127, g = t >> 7;
        float w0 = pm_w1[j], w1 = pm_w1[C + j], w2 = pm_w1[2 * C + j];
        float b  = pm_b1[j];
        #pragma unroll
        for (int i = 0; i < 16; ++i) {
            int e = g + i * 2;
            float val = fmaf(s_dp[e][0], w0, fmaf(s_dp[e][1], w1, fmaf(s_dp[e][2], w2, b)));
            s_a[e][j] = fmaxf(val, 0.0f);
        }
    }
    __syncthreads();

    const int jc = (t & 31) * 4;
    const int er = (t >> 5) * 4;

    // phase 2: delta = t1 @ pm_w2 + b2 ; h = q[col] - k[row] + delta
    float acc[4][4] = {};
    for (int kk = 0; kk < C; ++kk) {
        float4 b = *(const float4*)(pm_w2 + kk * C + jc);
        #pragma unroll
        for (int i = 0; i < 4; ++i) {
            float a = s_a[er + i][kk];
            acc[i][0] = fmaf(a, b.x, acc[i][0]);
            acc[i][1] = fmaf(a, b.y, acc[i][1]);
            acc[i][2] = fmaf(a, b.z, acc[i][2]);
            acc[i][3] = fmaf(a, b.w, acc[i][3]);
        }
    }
    {
        float4 bb = *(const float4*)(pm_b2 + jc);
        float hv[4][4];
        #pragma unroll
        for (int i = 0; i < 4; ++i) {
            int el = er + i;
            int e  = e0 + el;
            int r  = s_row[el], c = s_col[el];
            float4 qv = *(const float4*)(q + (size_t)c * C + jc);
            float4 kv = *(const float4*)(k + (size_t)r * C + jc);
            float d0 = acc[i][0] + bb.x;
            float d1 = acc[i][1] + bb.y;
            float d2 = acc[i][2] + bb.z;
            float d3 = acc[i][3] + bb.w;
            ushort4 dd;
            dd.x = f2bf_rn(d0); dd.y = f2bf_rn(d1); dd.z = f2bf_rn(d2); dd.w = f2bf_rn(d3);
            *(ushort4*)(dbf + (size_t)e * C + jc) = dd;
            hv[i][0] = qv.x - kv.x + d0;
            hv[i][1] = qv.y - kv.y + d1;
            hv[i][2] = qv.z - kv.z + d2;
            hv[i][3] = qv.w - kv.w + d3;
        }
        __syncthreads();   // everyone done reading t1 from s_a
        #pragma unroll
        for (int i = 0; i < 4; ++i) {
            s_a[er + i][jc + 0] = hv[i][0];
            s_a[er + i][jc + 1] = hv[i][1];
            s_a[er + i][jc + 2] = hv[i][2];
            s_a[er + i][jc + 3] = hv[i][3];
        }
    }
    __syncthreads();

    // phase 3: t2 = relu(h @ at_w1 + at_b1)
    float acc2[4][4] = {};
    for (int kk = 0; kk < C; ++kk) {
        float4 b = *(const float4*)(at_w1 + kk * C + jc);
        #pragma unroll
        for (int i = 0; i < 4; ++i) {
            float a = s_a[er + i][kk];
            acc2[i][0] = fmaf(a, b.x, acc2[i][0]);
            acc2[i][1] = fmaf(a, b.y, acc2[i][1]);
            acc2[i][2] = fmaf(a, b.z, acc2[i][2]);
            acc2[i][3] = fmaf(a, b.w, acc2[i][3]);
        }
    }
    {
        float4 ab = *(const float4*)(at_b1 + jc);
        #pragma unroll
        for (int i = 0; i < 4; ++i) {
            s_b[er + i][jc + 0] = fmaxf(acc2[i][0] + ab.x, 0.0f);
            s_b[er + i][jc + 1] = fmaxf(acc2[i][1] + ab.y, 0.0f);
            s_b[er + i][jc + 2] = fmaxf(acc2[i][2] + ab.z, 0.0f);
            s_b[er + i][jc + 3] = fmaxf(acc2[i][3] + ab.w, 0.0f);
        }
    }
    __syncthreads();

    // phase 4: logits = t2 @ at_w2 + at_b2
    {
        int e = t >> 3, l = t & 7;
        float sum = 0.0f;
        #pragma unroll
        for (int i = 0; i < 16; ++i) {
            int kk = l * 16 + i;
            sum = fmaf(s_b[e][kk], at_w2[kk], sum);
        }
        sum += __shfl_xor(sum, 1, 64);
        sum += __shfl_xor(sum, 2, 64);
        sum += __shfl_xor(sum, 4, 64);
        if (l == 0) logits[e0 + e] = sum + at_b2[0];
    }
}

// ---------------- K3: CSR build by destination ----------------
__global__ __launch_bounds__(256) void hist_kernel(const int* __restrict__ eidx,
                                                   int* __restrict__ counts)
{
    int e = blockIdx.x * 256 + threadIdx.x;
    if (e < EE) atomicAdd(&counts[eidx[EE + e]], 1);
}

__global__ __launch_bounds__(1024) void scan_kernel(const int* __restrict__ counts,
                                                    int* __restrict__ offsets, int n)
{
    __shared__ int wsum[16];
    __shared__ int wpre[16];
    __shared__ int tot_s;
    int t = threadIdx.x;
    int lane = t & 63, w = t >> 6;
    int carry = 0;
    for (int base = 0; base < n; base += 1024) {
        int i = base + t;
        int v = (i < n) ? counts[i] : 0;
        int incl = v;
        #pragma unroll
        for (int d = 1; d < 64; d <<= 1) {
            int u = __shfl_up(incl, d, 64);
            if (lane >= d) incl += u;
        }
        if (lane == 63) wsum[w] = incl;
        __syncthreads();
        if (t == 0) {
            int run = 0;
            #pragma unroll
            for (int ww = 0; ww < 16; ++ww) { wpre[ww] = run; run += wsum[ww]; }
            tot_s = run;
        }
        __syncthreads();
        if (i < n) offsets[i] = carry + wpre[w] + incl - v;
        carry += tot_s;
        __syncthreads();
    }
    if (t == 0) offsets[n] = carry;
}

__global__ __launch_bounds__(256) void fill_kernel(const int* __restrict__ eidx,
                                                   const int* __restrict__ offsets,
                                                   int* __restrict__ cursor,
                                                   int* __restrict__ elist)
{
    int e = blockIdx.x * 256 + threadIdx.x;
    if (e < EE) {
        int c = eidx[EE + e];
        int p = atomicAdd(&cursor[c], 1);
        elist[offsets[c] + p] = e;
    }
}

// ---------------- K4: per-node softmax + gather-sum ----------------
__global__ __launch_bounds__(256) void gather_kernel(
    const int* __restrict__ eidx, const int* __restrict__ offsets,
    const int* __restrict__ elist, const float* __restrict__ logits,
    const float* __restrict__ vmat, const unsigned short* __restrict__ dbf,
    float* __restrict__ out)
{
    int n = blockIdx.x * 2 + (threadIdx.x >> 7);
    int j = threadIdx.x & 127;
    if (n >= NN) return;
    int o0 = offsets[n], o1 = offsets[n + 1];

    float m = -1e30f;
    for (int i = o0; i < o1; ++i) m = fmaxf(m, logits[elist[i]]);
    float s = 0.0f;
    for (int i = o0; i < o1; ++i) s += __expf(logits[elist[i]] - m);
    float inv = (s > 0.0f) ? 1.0f / s : 0.0f;

    float acc = 0.0f;
    for (int i = o0; i < o1; ++i) {
        int e = elist[i];
        int r = eidx[e];
        float wgt = __expf(logits[e] - m) * inv;
        acc = fmaf(wgt, vmat[(size_t)r * C + j] + bf2f(dbf[(size_t)e * C + j]), acc);
    }
    out[(size_t)n * C + j] += acc;
}

// ---------------- launch ----------------
extern "C" void kernel_launch(void* const* d_in, const int* in_sizes, int n_in,
                              void* d_out, int out_size, void* d_ws, size_t ws_size,
                              hipStream_t stream)
{
    (void)in_sizes; (void)n_in; (void)out_size; (void)ws_size;
    const float* x      = (const float*)d_in[0];
    const float* pos    = (const float*)d_in[1];
    const int*   eidx   = (const int*)d_in[2];
    const float* Wq     = (const float*)d_in[3];
    const float* Wk     = (const float*)d_in[4];
    const float* Wv     = (const float*)d_in[5];
    const float* pm_w1  = (const float*)d_in[6];
    const float* pm_b1  = (const float*)d_in[7];
    const float* pm_w2  = (const float*)d_in[8];
    const float* pm_b2  = (const float*)d_in[9];
    const float* at_w1  = (const float*)d_in[10];
    const float* at_b1  = (const float*)d_in[11];
    const float* at_w2  = (const float*)d_in[12];
    const float* at_b2  = (const float*)d_in[13];
    const float* root_w = (const float*)d_in[14];
    const float* root_b = (const float*)d_in[15];
    float* out = (float*)d_out;

    char* w = (char*)d_ws;
    float* q        = (float*)w;          w += (size_t)NN * C * 4;
    float* k        = (float*)w;          w += (size_t)NN * C * 4;
    float* v        = (float*)w;          w += (size_t)NN * C * 4;
    float* logits   = (float*)w;          w += (size_t)EE * 4;
    unsigned short* dbf = (unsigned short*)w; w += (size_t)EE * C * 2;
    int* counts     = (int*)w;            w += (size_t)NN * 4;
    int* cursor     = (int*)w;            w += (size_t)NN * 4;
    int* offsets    = (int*)w;            w += (size_t)(NN + 1) * 4;
    int* elist      = (int*)w;            w += (size_t)EE * 4;

    hipMemsetAsync(counts, 0, (size_t)NN * 4, stream);
    hipMemsetAsync(cursor, 0, (size_t)NN * 4, stream);

    node_gemm<<<dim3((NN + 31) / 32, 4), 256, 0, stream>>>(
        x, Wq, Wk, Wv, root_w, root_b, q, k, v, out);

    edge_kernel<<<EE / 32, 256, 0, stream>>>(
        pos, eidx, q, k, pm_w1, pm_b1, pm_w2, pm_b2,
        at_w1, at_b1, at_w2, at_b2, dbf, logits);

    hist_kernel<<<(EE + 255) / 256, 256, 0, stream>>>(eidx, counts);
    scan_kernel<<<1, 1024, 0, stream>>>(counts, offsets, NN);
    fill_kernel<<<(EE + 255) / 256, 256, 0, stream>>>(eidx, offsets, cursor, elist);

    gather_kernel<<<(NN + 1) / 2, 256, 0, stream>>>(
        eidx, offsets, elist, logits, v, dbf, out);
}

// Round 2
// 567.392 us; speedup vs baseline: 1.6161x; 1.6161x over previous
//
#include <hip/hip_runtime.h>
#include <hip/hip_bf16.h>

#define NN 30000
#define EE 480000
#define C  128
#define NTILES (EE / 64)   // 7500
#define EGRID 2500

typedef __attribute__((ext_vector_type(8))) short          short8v;
typedef __attribute__((ext_vector_type(8))) unsigned short ushort8v;
typedef __attribute__((ext_vector_type(8))) short          frag16;   // 8 bf16 (4 VGPRs)
typedef __attribute__((ext_vector_type(4))) float          f32x4;

#define MFMA16(a, b, c) __builtin_amdgcn_mfma_f32_16x16x32_bf16(a, b, c, 0, 0, 0)

static __device__ __forceinline__ unsigned short f2bf_rn(float f) {
    unsigned int u = __float_as_uint(f);
    unsigned int r = (u + 0x7fffu + ((u >> 16) & 1u)) >> 16;
    return (unsigned short)r;
}
static __device__ __forceinline__ float bf2f(unsigned short s) {
    return __uint_as_float(((unsigned int)s) << 16);
}

// ---------------- P0: weight precomputes ----------------
// Wc = pm_w2 @ at_w1 ; Wqa = Wq @ at_w1 ; Wka = Wk @ at_w1 ;
// bias_c = at_b1 + pm_b2 @ at_w1
__global__ __launch_bounds__(256) void prep_kernel(
    const float* __restrict__ pm_w2, const float* __restrict__ at_w1,
    const float* __restrict__ Wq, const float* __restrict__ Wk,
    const float* __restrict__ pm_b2, const float* __restrict__ at_b1,
    float* __restrict__ Wc, float* __restrict__ Wqa, float* __restrict__ Wka,
    float* __restrict__ bias_c)
{
    const int which = blockIdx.y;
    const int t = threadIdx.x;
    if (which == 3) {
        if (blockIdx.x == 0 && t < C) {
            float s = at_b1[t];
            for (int k = 0; k < C; ++k) s = fmaf(pm_b2[k], at_w1[k * C + t], s);
            bias_c[t] = s;
        }
        return;
    }
    const float* A = (which == 0) ? pm_w2 : (which == 1) ? Wq : Wk;
    float* O = (which == 0) ? Wc : (which == 1) ? Wqa : Wka;

    __shared__ float sA[2][C];
    int i = blockIdx.x * 2 + (t >> 7), j = t & 127;
    sA[t >> 7][j] = A[i * C + j];
    __syncthreads();
    float s = 0.f;
    for (int k = 0; k < C; ++k) s = fmaf(sA[t >> 7][k], at_w1[k * C + j], s);
    O[i * C + j] = s;
}

// ---------------- K1: node GEMMs ----------------
// m: 0->qbf 1->kbf 2->vbf 3->out(f32,+bias) 4->qabf 5->kabf
__global__ __launch_bounds__(256) void node_gemm(
    const float* __restrict__ x,
    const float* __restrict__ Wq, const float* __restrict__ Wk,
    const float* __restrict__ Wv, const float* __restrict__ Wr,
    const float* __restrict__ Wqa, const float* __restrict__ Wka,
    const float* __restrict__ root_b,
    unsigned short* __restrict__ qbf, unsigned short* __restrict__ kbf,
    unsigned short* __restrict__ vbf, unsigned short* __restrict__ qabf,
    unsigned short* __restrict__ kabf, float* __restrict__ out)
{
    const int m = blockIdx.y;
    const float* W;
    switch (m) {
        case 0: W = Wq; break; case 1: W = Wk; break; case 2: W = Wv; break;
        case 3: W = Wr; break; case 4: W = Wqa; break; default: W = Wka;
    }

    const int n0 = blockIdx.x * 32;
    const int t  = threadIdx.x;
    __shared__ float sx[32][C];

    for (int idx = t; idx < 32 * C; idx += 256) {
        int i = idx >> 7, c = idx & 127;
        int n = n0 + i;
        sx[i][c] = (n < NN) ? x[(size_t)n * C + c] : 0.0f;
    }
    __syncthreads();

    const int jc = (t & 31) * 4;
    const int er = (t >> 5) * 4;
    float acc[4][4] = {};

    for (int kk = 0; kk < C; ++kk) {
        float4 b = *(const float4*)(W + kk * C + jc);
        #pragma unroll
        for (int i = 0; i < 4; ++i) {
            float a = sx[er + i][kk];
            acc[i][0] = fmaf(a, b.x, acc[i][0]);
            acc[i][1] = fmaf(a, b.y, acc[i][1]);
            acc[i][2] = fmaf(a, b.z, acc[i][2]);
            acc[i][3] = fmaf(a, b.w, acc[i][3]);
        }
    }

    if (m == 3) {
        float4 bias = *(const float4*)(root_b + jc);
        #pragma unroll
        for (int i = 0; i < 4; ++i) {
            int n = n0 + er + i;
            if (n < NN) {
                float4 r;
                r.x = acc[i][0] + bias.x; r.y = acc[i][1] + bias.y;
                r.z = acc[i][2] + bias.z; r.w = acc[i][3] + bias.w;
                *(float4*)(out + (size_t)n * C + jc) = r;
            }
        }
    } else {
        unsigned short* O = (m == 0) ? qbf : (m == 1) ? kbf : (m == 2) ? vbf
                          : (m == 4) ? qabf : kabf;
        #pragma unroll
        for (int i = 0; i < 4; ++i) {
            int n = n0 + er + i;
            if (n < NN) {
                ushort4 u;
                u.x = f2bf_rn(acc[i][0]); u.y = f2bf_rn(acc[i][1]);
                u.z = f2bf_rn(acc[i][2]); u.w = f2bf_rn(acc[i][3]);
                *(ushort4*)(O + (size_t)n * C + jc) = u;
            }
        }
    }
}

// ---------------- K3: CSR build by destination ----------------
__global__ __launch_bounds__(256) void hist_kernel(const int* __restrict__ eidx,
                                                   int* __restrict__ counts)
{
    int e = blockIdx.x * 256 + threadIdx.x;
    if (e < EE) atomicAdd(&counts[eidx[EE + e]], 1);
}

__global__ __launch_bounds__(1024) void scan_kernel(const int* __restrict__ counts,
                                                    int* __restrict__ offsets, int n)
{
    __shared__ int wsum[16];
    __shared__ int wpre[16];
    __shared__ int tot_s;
    int t = threadIdx.x;
    int lane = t & 63, w = t >> 6;
    int carry = 0;
    for (int base = 0; base < n; base += 1024) {
        int i = base + t;
        int v = (i < n) ? counts[i] : 0;
        int incl = v;
        #pragma unroll
        for (int d = 1; d < 64; d <<= 1) {
            int u = __shfl_up(incl, d, 64);
            if (lane >= d) incl += u;
        }
        if (lane == 63) wsum[w] = incl;
        __syncthreads();
        if (t == 0) {
            int run = 0;
            #pragma unroll
            for (int ww = 0; ww < 16; ++ww) { wpre[ww] = run; run += wsum[ww]; }
            tot_s = run;
        }
        __syncthreads();
        if (i < n) offsets[i] = carry + wpre[w] + incl - v;
        carry += tot_s;
        __syncthreads();
    }
    if (t == 0) offsets[n] = carry;
}

__global__ __launch_bounds__(256) void fill_kernel(const int* __restrict__ eidx,
                                                   const int* __restrict__ offsets,
                                                   int* __restrict__ cursor,
                                                   int* __restrict__ perm,
                                                   int* __restrict__ rows_sorted)
{
    int e = blockIdx.x * 256 + threadIdx.x;
    if (e < EE) {
        int c = eidx[EE + e];
        int p = atomicAdd(&cursor[c], 1);
        int slot = offsets[c] + p;
        perm[e] = slot;
        rows_sorted[slot] = eidx[e];
    }
}

// ---------------- K2: per-edge fused MLPs via MFMA ----------------
// Per tile of 64 edges:
//   t1 = relu(dpos@pm_w1 + pm_b1)                      (bf16, LDS, swizzled)
//   delta = t1@pm_w2 + pm_b2          -> dbf[slot]     (GEMM1, MFMA)
//   t2pre = t1@Wc + (qa[col]-ka[row]) + bias_c         (GEMM2, MFMA; qka staged)
//   logits[slot] = relu(t2pre)@at_w2 + at_b2
__global__ __launch_bounds__(256, 2) void edge_kernel(
    const float* __restrict__ pos, const int* __restrict__ eidx,
    const int* __restrict__ perm,
    const unsigned short* __restrict__ qabf, const unsigned short* __restrict__ kabf,
    const float* __restrict__ pm_w1, const float* __restrict__ pm_b1,
    const float* __restrict__ pm_w2, const float* __restrict__ pm_b2,
    const float* __restrict__ Wc, const float* __restrict__ bias_c,
    const float* __restrict__ at_w2, const float* __restrict__ at_b2,
    unsigned short* __restrict__ dbf, float* __restrict__ logits)
{
    __shared__ short s_t1[64 * C];     // bf16, XOR-swizzled
    __shared__ short s_qka[64 * C];    // bf16, XOR-swizzled
    __shared__ short s_delta[64 * C];  // bf16, XOR-swizzled
    __shared__ float s_w14[C][4];      // pm_w1 rows 0..2 + pm_b1, per col
    __shared__ float s_dp[64][4];
    __shared__ int   s_row[64], s_col[64], s_slot[64];
    __shared__ float s_logit[64][4];

    const int t    = threadIdx.x;
    const int wv   = t >> 6;
    const int lane = t & 63;
    const int ln15 = lane & 15;
    const int lg   = lane >> 4;
    const int jw   = wv * 32;
    const int colA = jw + ln15, colB = colA + 16;

    for (int j = t; j < C; j += 256) {
        s_w14[j][0] = pm_w1[j];
        s_w14[j][1] = pm_w1[C + j];
        s_w14[j][2] = pm_w1[2 * C + j];
        s_w14[j][3] = pm_b1[j];
    }

    const float b2A = pm_b2[colA], b2B = pm_b2[colB];
    const float bcA = bias_c[colA], bcB = bias_c[colB];
    const float w2A = at_w2[colA], w2B = at_w2[colB];
    const float atb2 = at_b2[0];

    // B fragments in registers: [gemm][ntile][kstep]
    frag16 fB[2][2][4];
    #pragma unroll
    for (int g = 0; g < 2; ++g) {
        const float* W = g ? Wc : pm_w2;
        #pragma unroll
        for (int nt = 0; nt < 2; ++nt) {
            int col = jw + nt * 16 + ln15;
            #pragma unroll
            for (int ks = 0; ks < 4; ++ks) {
                frag16 f;
                #pragma unroll
                for (int e = 0; e < 8; ++e) {
                    int k = ks * 32 + lg * 8 + e;
                    f[e] = (short)f2bf_rn(W[k * C + col]);
                }
                fB[g][nt][ks] = f;
            }
        }
    }

    for (int tile = blockIdx.x; tile < NTILES; tile += EGRID) {
        const int e0 = tile * 64;

        if (t < 64) {
            int e = e0 + t;
            int rr = eidx[e], cc = eidx[EE + e];
            s_row[t] = rr; s_col[t] = cc; s_slot[t] = perm[e];
            s_dp[t][0] = pos[rr * 3 + 0] - pos[cc * 3 + 0];
            s_dp[t][1] = pos[rr * 3 + 1] - pos[cc * 3 + 1];
            s_dp[t][2] = pos[rr * 3 + 2] - pos[cc * 3 + 2];
            s_dp[t][3] = 0.f;
        }
        __syncthreads();

        // (b) t1 tile
        {
            const int rt = t >> 4, ct8 = (t & 15) * 8;
            #pragma unroll
            for (int rr2 = 0; rr2 < 4; ++rr2) {
                int row = rt * 4 + rr2;
                float4 dp = *(const float4*)(&s_dp[row][0]);
                short8v o;
                #pragma unroll
                for (int e = 0; e < 8; ++e) {
                    float4 wj = *(const float4*)(&s_w14[ct8 + e][0]);
                    float v = fmaf(dp.x, wj.x, fmaf(dp.y, wj.y, fmaf(dp.z, wj.z, wj.w)));
                    o[e] = (short)f2bf_rn(fmaxf(v, 0.f));
                }
                int off = (row * 256 + ct8 * 2) ^ ((row & 7) << 4);
                *(short8v*)((char*)s_t1 + off) = o;
            }
        }
        // (c) qka = qa[col] - ka[row]
        {
            const int rq = t >> 2, q4 = t & 3;
            const unsigned short* qrow = qabf + (size_t)s_col[rq] * C;
            const unsigned short* krow = kabf + (size_t)s_row[rq] * C;
            #pragma unroll
            for (int i = 0; i < 4; ++i) {
                int j0 = q4 * 32 + i * 8;
                ushort8v qa8 = *(const ushort8v*)(qrow + j0);
                ushort8v ka8 = *(const ushort8v*)(krow + j0);
                short8v o;
                #pragma unroll
                for (int e = 0; e < 8; ++e)
                    o[e] = (short)f2bf_rn(bf2f(qa8[e]) - bf2f(ka8[e]));
                int off = (rq * 256 + j0 * 2) ^ ((rq & 7) << 4);
                *(short8v*)((char*)s_qka + off) = o;
            }
        }
        __syncthreads();

        // GEMM1 (delta) + GEMM2 (logit pre) — shared A fragments
        f32x4 acc1[4][2], acc2[4][2];
        const f32x4 zz = {0.f, 0.f, 0.f, 0.f};
        #pragma unroll
        for (int mt = 0; mt < 4; ++mt) {
            acc1[mt][0] = zz; acc1[mt][1] = zz;
            acc2[mt][0] = zz; acc2[mt][1] = zz;
        }
        #pragma unroll
        for (int mt = 0; mt < 4; ++mt) {
            int rowa = mt * 16 + ln15;
            #pragma unroll
            for (int ks = 0; ks < 4; ++ks) {
                int off = (rowa * 256 + (ks * 32 + lg * 8) * 2) ^ ((rowa & 7) << 4);
                frag16 a = *(const frag16*)((const char*)s_t1 + off);
                acc1[mt][0] = MFMA16(a, fB[0][0][ks], acc1[mt][0]);
                acc1[mt][1] = MFMA16(a, fB[0][1][ks], acc1[mt][1]);
                acc2[mt][0] = MFMA16(a, fB[1][0][ks], acc2[mt][0]);
                acc2[mt][1] = MFMA16(a, fB[1][1][ks], acc2[mt][1]);
            }
        }

        // epilogue: delta -> s_delta ; logits partials -> s_logit
        #pragma unroll
        for (int mt = 0; mt < 4; ++mt) {
            #pragma unroll
            for (int r = 0; r < 4; ++r) {
                int row = mt * 16 + lg * 4 + r;
                int swz = (row & 7) << 4;
                int offA = (row * 256 + colA * 2) ^ swz;
                int offB = (row * 256 + colB * 2) ^ swz;
                float dA = acc1[mt][0][r] + b2A;
                float dB = acc1[mt][1][r] + b2B;
                *(short*)((char*)s_delta + offA) = (short)f2bf_rn(dA);
                *(short*)((char*)s_delta + offB) = (short)f2bf_rn(dB);
                float qkA = bf2f(*(const unsigned short*)((const char*)s_qka + offA));
                float qkB = bf2f(*(const unsigned short*)((const char*)s_qka + offB));
                float tA = fmaxf(acc2[mt][0][r] + qkA + bcA, 0.f);
                float tB = fmaxf(acc2[mt][1][r] + qkB + bcB, 0.f);
                float p = fmaf(tA, w2A, tB * w2B);
                p += __shfl_xor(p, 1, 64);
                p += __shfl_xor(p, 2, 64);
                p += __shfl_xor(p, 4, 64);
                p += __shfl_xor(p, 8, 64);
                if (ln15 == 0) s_logit[row][wv] = p;
            }
        }
        __syncthreads();

        // (g) write delta (CSR slot, row-major) + logits
        {
            const int rq = t >> 2, q4 = t & 3;
            int slot = s_slot[rq];
            unsigned short* drow = dbf + (size_t)slot * C;
            #pragma unroll
            for (int i = 0; i < 4; ++i) {
                int j0 = q4 * 32 + i * 8;
                int off = (rq * 256 + j0 * 2) ^ ((rq & 7) << 4);
                short8v d8 = *(const short8v*)((const char*)s_delta + off);
                *(short8v*)(void*)(drow + j0) = d8;
            }
            if (t < 64)
                logits[s_slot[t]] = s_logit[t][0] + s_logit[t][1]
                                  + s_logit[t][2] + s_logit[t][3] + atb2;
        }
        __syncthreads();
    }
}

// ---------------- K4: per-node softmax + gather-sum (CSR-sorted) ----------------
__global__ __launch_bounds__(256) void gather_kernel(
    const int* __restrict__ offsets, const int* __restrict__ rows_sorted,
    const float* __restrict__ logits, const unsigned short* __restrict__ vbf,
    const unsigned short* __restrict__ dbf, float* __restrict__ out)
{
    int n = blockIdx.x * 2 + (threadIdx.x >> 7);
    int j = threadIdx.x & 127;
    if (n >= NN) return;
    int o0 = offsets[n], o1 = offsets[n + 1];

    float m = -1e30f;
    for (int i = o0; i < o1; ++i) m = fmaxf(m, logits[i]);
    float s = 0.0f;
    for (int i = o0; i < o1; ++i) s += __expf(logits[i] - m);
    float inv = (s > 0.0f) ? 1.0f / s : 0.0f;

    float acc = 0.0f;
    for (int i = o0; i < o1; ++i) {
        float wgt = __expf(logits[i] - m) * inv;
        int r = rows_sorted[i];
        acc = fmaf(wgt, bf2f(vbf[(size_t)r * C + j]) + bf2f(dbf[(size_t)i * C + j]), acc);
    }
    out[(size_t)n * C + j] += acc;
}

// ---------------- launch ----------------
extern "C" void kernel_launch(void* const* d_in, const int* in_sizes, int n_in,
                              void* d_out, int out_size, void* d_ws, size_t ws_size,
                              hipStream_t stream)
{
    (void)in_sizes; (void)n_in; (void)out_size; (void)ws_size;
    const float* x      = (const float*)d_in[0];
    const float* pos    = (const float*)d_in[1];
    const int*   eidx   = (const int*)d_in[2];
    const float* Wq     = (const float*)d_in[3];
    const float* Wk     = (const float*)d_in[4];
    const float* Wv     = (const float*)d_in[5];
    const float* pm_w1  = (const float*)d_in[6];
    const float* pm_b1  = (const float*)d_in[7];
    const float* pm_w2  = (const float*)d_in[8];
    const float* pm_b2  = (const float*)d_in[9];
    const float* at_w1  = (const float*)d_in[10];
    const float* at_b1  = (const float*)d_in[11];
    const float* at_w2  = (const float*)d_in[12];
    const float* at_b2  = (const float*)d_in[13];
    const float* root_w = (const float*)d_in[14];
    const float* root_b = (const float*)d_in[15];
    float* out = (float*)d_out;

    char* w = (char*)d_ws;
    unsigned short* qbf  = (unsigned short*)w; w += (size_t)NN * C * 2;
    unsigned short* kbf  = (unsigned short*)w; w += (size_t)NN * C * 2;
    unsigned short* vbf  = (unsigned short*)w; w += (size_t)NN * C * 2;
    unsigned short* qabf = (unsigned short*)w; w += (size_t)NN * C * 2;
    unsigned short* kabf = (unsigned short*)w; w += (size_t)NN * C * 2;
    unsigned short* dbf  = (unsigned short*)w; w += (size_t)EE * C * 2;
    float* logits   = (float*)w; w += (size_t)EE * 4;
    float* Wc       = (float*)w; w += (size_t)C * C * 4;
    float* Wqa      = (float*)w; w += (size_t)C * C * 4;
    float* Wka      = (float*)w; w += (size_t)C * C * 4;
    float* bias_c   = (float*)w; w += 512;
    int* perm        = (int*)w; w += (size_t)EE * 4;
    int* rows_sorted = (int*)w; w += (size_t)EE * 4;
    int* counts      = (int*)w; w += (size_t)NN * 4;
    int* cursor      = (int*)w; w += (size_t)NN * 4;
    int* offsets     = (int*)w; w += (size_t)(NN + 1) * 4;

    hipMemsetAsync(counts, 0, (size_t)NN * 4, stream);
    hipMemsetAsync(cursor, 0, (size_t)NN * 4, stream);

    prep_kernel<<<dim3(64, 4), 256, 0, stream>>>(
        pm_w2, at_w1, Wq, Wk, pm_b2, at_b1, Wc, Wqa, Wka, bias_c);

    node_gemm<<<dim3((NN + 31) / 32, 6), 256, 0, stream>>>(
        x, Wq, Wk, Wv, root_w, Wqa, Wka, root_b,
        qbf, kbf, vbf, qabf, kabf, out);

    hist_kernel<<<(EE + 255) / 256, 256, 0, stream>>>(eidx, counts);
    scan_kernel<<<1, 1024, 0, stream>>>(counts, offsets, NN);
    fill_kernel<<<(EE + 255) / 256, 256, 0, stream>>>(eidx, offsets, cursor,
                                                      perm, rows_sorted);

    edge_kernel<<<EGRID, 256, 0, stream>>>(
        pos, eidx, perm, qabf, kabf, pm_w1, pm_b1, pm_w2, pm_b2,
        Wc, bias_c, at_w2, at_b2, dbf, logits);

    gather_kernel<<<(NN + 1) / 2, 256, 0, stream>>>(
        offsets, rows_sorted, logits, vbf, dbf, out);
}

// Round 3
// 476.947 us; speedup vs baseline: 1.9226x; 1.1896x over previous
//
#include <hip/hip_runtime.h>
#include <hip/hip_bf16.h>

#define NN 30000
#define EE 480000
#define C  128
#define NTILES (EE / 64)   // 7500
#define EGRID 2500

typedef __attribute__((ext_vector_type(8))) short          short8v;
typedef __attribute__((ext_vector_type(8))) unsigned short ushort8v;
typedef __attribute__((ext_vector_type(8))) short          frag16;   // 8 bf16
typedef __attribute__((ext_vector_type(4))) float          f32x4;

#define MFMA16(a, b, c) __builtin_amdgcn_mfma_f32_16x16x32_bf16(a, b, c, 0, 0, 0)

static __device__ __forceinline__ unsigned short f2bf_rn(float f) {
    unsigned int u = __float_as_uint(f);
    unsigned int r = (u + 0x7fffu + ((u >> 16) & 1u)) >> 16;
    return (unsigned short)r;
}
static __device__ __forceinline__ float bf2f(unsigned short s) {
    return __uint_as_float(((unsigned int)s) << 16);
}

// ---------------- P0: weight precomputes (all outputs TRANSPOSED bf16) ------
// which 0: WcT  = T(pm_w2 @ at_w1)      1: WqaT = T(Wq @ at_w1)
//       2: WkaT = T(Wk @ at_w1)         3: bias_c = at_b1 + pm_b2 @ at_w1
//       4: WvT  = T(Wv)   5: WrT = T(root_w)   6: Wp2T = T(pm_w2)
__global__ __launch_bounds__(256) void prep_kernel(
    const float* __restrict__ pm_w2, const float* __restrict__ at_w1,
    const float* __restrict__ Wq, const float* __restrict__ Wk,
    const float* __restrict__ Wv, const float* __restrict__ root_w,
    const float* __restrict__ pm_b2, const float* __restrict__ at_b1,
    unsigned short* __restrict__ WcT, unsigned short* __restrict__ WqaT,
    unsigned short* __restrict__ WkaT, unsigned short* __restrict__ WvT,
    unsigned short* __restrict__ WrT, unsigned short* __restrict__ Wp2T,
    float* __restrict__ bias_c)
{
    const int which = blockIdx.y;
    const int t = threadIdx.x;
    const int i = blockIdx.x * 2 + (t >> 7), j = t & 127;

    if (which == 3) {
        if (blockIdx.x == 0 && t < C) {
            float s = at_b1[t];
            for (int k = 0; k < C; ++k) s = fmaf(pm_b2[k], at_w1[k * C + t], s);
            bias_c[t] = s;
        }
        return;
    }
    if (which >= 4) {
        const float* A = (which == 4) ? Wv : (which == 5) ? root_w : pm_w2;
        unsigned short* OT = (which == 4) ? WvT : (which == 5) ? WrT : Wp2T;
        OT[j * C + i] = f2bf_rn(A[i * C + j]);
        return;
    }
    const float* A = (which == 0) ? pm_w2 : (which == 1) ? Wq : Wk;
    unsigned short* OT = (which == 0) ? WcT : (which == 1) ? WqaT : WkaT;

    __shared__ float sA[2][C];
    sA[t >> 7][j] = A[i * C + j];
    __syncthreads();
    float s = 0.f;
    for (int k = 0; k < C; ++k) s = fmaf(sA[t >> 7][k], at_w1[k * C + j], s);
    OT[j * C + i] = f2bf_rn(s);
}

// ---------------- x -> bf16 ----------------
__global__ __launch_bounds__(256) void convert_kernel(const float* __restrict__ x,
                                                      unsigned short* __restrict__ xbf)
{
    int i = (blockIdx.x * 256 + threadIdx.x) * 4;
    if (i < NN * C) {
        float4 v = *(const float4*)(x + i);
        ushort4 u;
        u.x = f2bf_rn(v.x); u.y = f2bf_rn(v.y); u.z = f2bf_rn(v.z); u.w = f2bf_rn(v.w);
        *(ushort4*)(xbf + i) = u;
    }
}

// ---------------- K1: node GEMMs via MFMA (swapped operands) ----------------
// m: 0->vbf  1->qabf  2->kabf  3->out (f32, + root_b)
__global__ __launch_bounds__(256, 4) void node_gemm(
    const unsigned short* __restrict__ xbf,
    const unsigned short* __restrict__ WvT, const unsigned short* __restrict__ WqaT,
    const unsigned short* __restrict__ WkaT, const unsigned short* __restrict__ WrT,
    const float* __restrict__ root_b,
    unsigned short* __restrict__ vbf, unsigned short* __restrict__ qabf,
    unsigned short* __restrict__ kabf, float* __restrict__ out)
{
    __shared__ short s_x[64 * C];   // bf16, swizzled
    const int nb = blockIdx.x * 64;
    const int t = threadIdx.x;
    const int lane = t & 63, wv = t >> 6;
    const int ln15 = lane & 15, lg = lane >> 4;
    const int jw = wv * 32;

    {   // stage x tile
        const int rq = t >> 2, q4 = t & 3;
        int row = nb + rq;
        #pragma unroll
        for (int i2 = 0; i2 < 4; ++i2) {
            int j0 = q4 * 32 + i2 * 8;
            short8v v = {0,0,0,0,0,0,0,0};
            if (row < NN) v = *(const short8v*)(xbf + (size_t)row * C + j0);
            int off = (rq * 256 + j0 * 2) ^ ((rq & 7) << 4);
            *(short8v*)((char*)s_x + off) = v;
        }
    }
    __syncthreads();

    for (int m = 0; m < 4; ++m) {
        const unsigned short* WT;
        switch (m) {
            case 0: WT = WvT;  break; case 1: WT = WqaT; break;
            case 2: WT = WkaT; break; default: WT = WrT;
        }
        frag16 aW[2][4];
        #pragma unroll
        for (int nt = 0; nt < 2; ++nt)
            #pragma unroll
            for (int ks = 0; ks < 4; ++ks)
                aW[nt][ks] = *(const frag16*)(WT + (size_t)(jw + nt * 16 + ln15) * C
                                                 + ks * 32 + lg * 8);
        f32x4 acc[4][2];
        const f32x4 zz = {0.f, 0.f, 0.f, 0.f};
        #pragma unroll
        for (int mt = 0; mt < 4; ++mt) { acc[mt][0] = zz; acc[mt][1] = zz; }

        #pragma unroll
        for (int mt = 0; mt < 4; ++mt) {
            int row = mt * 16 + ln15;
            #pragma unroll
            for (int ks = 0; ks < 4; ++ks) {
                int off = (row * 256 + (ks * 32 + lg * 8) * 2) ^ ((row & 7) << 4);
                frag16 b = *(const frag16*)((const char*)s_x + off);
                acc[mt][0] = MFMA16(aW[0][ks], b, acc[mt][0]);
                acc[mt][1] = MFMA16(aW[1][ks], b, acc[mt][1]);
            }
        }

        if (m == 3) {
            #pragma unroll
            for (int nt = 0; nt < 2; ++nt) {
                int col0 = jw + nt * 16 + lg * 4;
                float4 rb = *(const float4*)(root_b + col0);
                #pragma unroll
                for (int mt = 0; mt < 4; ++mt) {
                    int node = nb + mt * 16 + ln15;
                    if (node < NN) {
                        float4 o;
                        o.x = acc[mt][nt][0] + rb.x; o.y = acc[mt][nt][1] + rb.y;
                        o.z = acc[mt][nt][2] + rb.z; o.w = acc[mt][nt][3] + rb.w;
                        *(float4*)(out + (size_t)node * C + col0) = o;
                    }
                }
            }
        } else {
            unsigned short* OB = (m == 0) ? vbf : (m == 1) ? qabf : kabf;
            #pragma unroll
            for (int nt = 0; nt < 2; ++nt) {
                int col0 = jw + nt * 16 + lg * 4;
                #pragma unroll
                for (int mt = 0; mt < 4; ++mt) {
                    int node = nb + mt * 16 + ln15;
                    if (node < NN) {
                        ushort4 u;
                        u.x = f2bf_rn(acc[mt][nt][0]); u.y = f2bf_rn(acc[mt][nt][1]);
                        u.z = f2bf_rn(acc[mt][nt][2]); u.w = f2bf_rn(acc[mt][nt][3]);
                        *(ushort4*)(OB + (size_t)node * C + col0) = u;
                    }
                }
            }
        }
    }
}

// ---------------- K3: CSR build by destination ----------------
__global__ __launch_bounds__(256) void hist_kernel(const int* __restrict__ eidx,
                                                   int* __restrict__ counts)
{
    int e = blockIdx.x * 256 + threadIdx.x;
    if (e < EE) atomicAdd(&counts[eidx[EE + e]], 1);
}

__global__ __launch_bounds__(1024) void scan_kernel(const int* __restrict__ counts,
                                                    int* __restrict__ offsets, int n)
{
    __shared__ int wsum[16];
    __shared__ int wpre[16];
    __shared__ int tot_s;
    int t = threadIdx.x;
    int lane = t & 63, w = t >> 6;
    int carry = 0;
    for (int base = 0; base < n; base += 1024) {
        int i = base + t;
        int v = (i < n) ? counts[i] : 0;
        int incl = v;
        #pragma unroll
        for (int d = 1; d < 64; d <<= 1) {
            int u = __shfl_up(incl, d, 64);
            if (lane >= d) incl += u;
        }
        if (lane == 63) wsum[w] = incl;
        __syncthreads();
        if (t == 0) {
            int run = 0;
            #pragma unroll
            for (int ww = 0; ww < 16; ++ww) { wpre[ww] = run; run += wsum[ww]; }
            tot_s = run;
        }
        __syncthreads();
        if (i < n) offsets[i] = carry + wpre[w] + incl - v;
        carry += tot_s;
        __syncthreads();
    }
    if (t == 0) offsets[n] = carry;
}

__global__ __launch_bounds__(256) void fill_kernel(const int* __restrict__ eidx,
                                                   const float* __restrict__ pos,
                                                   const int* __restrict__ offsets,
                                                   int* __restrict__ cursor,
                                                   int* __restrict__ rows_sorted,
                                                   int* __restrict__ cols_sorted,
                                                   float* __restrict__ dpos4)
{
    int e = blockIdx.x * 256 + threadIdx.x;
    if (e < EE) {
        int r = eidx[e];
        int c = eidx[EE + e];
        int p = atomicAdd(&cursor[c], 1);
        int slot = offsets[c] + p;
        rows_sorted[slot] = r;
        cols_sorted[slot] = c;
        float4 d;
        d.x = pos[r * 3 + 0] - pos[c * 3 + 0];
        d.y = pos[r * 3 + 1] - pos[c * 3 + 1];
        d.z = pos[r * 3 + 2] - pos[c * 3 + 2];
        d.w = 0.f;
        *(float4*)(dpos4 + (size_t)slot * 4) = d;
    }
}

// ---------------- K2: per-edge logits via MFMA (swapped) ----------------
// t1 = relu(dpos@pm_w1+pm_b1); pre = t1@Wc + qa[col]-ka[row] + bias_c;
// logits[slot] = relu(pre)@at_w2 + at_b2
__global__ __launch_bounds__(256, 4) void edge_kernel(
    const int* __restrict__ rows_sorted, const int* __restrict__ cols_sorted,
    const float* __restrict__ dpos4,
    const unsigned short* __restrict__ qabf, const unsigned short* __restrict__ kabf,
    const float* __restrict__ pm_w1, const float* __restrict__ pm_b1,
    const unsigned short* __restrict__ WcT, const float* __restrict__ bias_c,
    const float* __restrict__ at_w2, const float* __restrict__ at_b2,
    float* __restrict__ logits)
{
    __shared__ short s_t1[64 * C];    // bf16, swizzled
    __shared__ short s_qka[64 * C];   // bf16, swizzled
    __shared__ float s_w14[C][4];
    __shared__ float s_dp[64][4];
    __shared__ int   s_row[64], s_col[64];
    __shared__ float s_logit[64][4];

    const int t = threadIdx.x;
    const int lane = t & 63, wv = t >> 6;
    const int ln15 = lane & 15, lg = lane >> 4;
    const int jw = wv * 32;

    for (int j = t; j < C; j += 256) {
        s_w14[j][0] = pm_w1[j];
        s_w14[j][1] = pm_w1[C + j];
        s_w14[j][2] = pm_w1[2 * C + j];
        s_w14[j][3] = pm_b1[j];
    }

    // per-lane constants: cols jw + nt*16 + lg*4 + r
    float bcv[8], w2v[8];
    #pragma unroll
    for (int nt = 0; nt < 2; ++nt) {
        int col0 = jw + nt * 16 + lg * 4;
        float4 b4 = *(const float4*)(bias_c + col0);
        float4 w4 = *(const float4*)(at_w2 + col0);
        bcv[nt * 4 + 0] = b4.x; bcv[nt * 4 + 1] = b4.y;
        bcv[nt * 4 + 2] = b4.z; bcv[nt * 4 + 3] = b4.w;
        w2v[nt * 4 + 0] = w4.x; w2v[nt * 4 + 1] = w4.y;
        w2v[nt * 4 + 2] = w4.z; w2v[nt * 4 + 3] = w4.w;
    }
    const float atb2 = at_b2[0];

    frag16 aW[2][4];
    #pragma unroll
    for (int nt = 0; nt < 2; ++nt)
        #pragma unroll
        for (int ks = 0; ks < 4; ++ks)
            aW[nt][ks] = *(const frag16*)(WcT + (size_t)(jw + nt * 16 + ln15) * C
                                             + ks * 32 + lg * 8);

    for (int tile = blockIdx.x; tile < NTILES; tile += EGRID) {
        const int s0 = tile * 64;

        __syncthreads();
        if (t < 64) {
            s_row[t] = rows_sorted[s0 + t];
            s_col[t] = cols_sorted[s0 + t];
            *(float4*)(&s_dp[t][0]) = *(const float4*)(dpos4 + (size_t)(s0 + t) * 4);
        }
        __syncthreads();

        // stage t1
        {
            const int rt = t >> 4, ct8 = (t & 15) * 8;
            #pragma unroll
            for (int rr2 = 0; rr2 < 4; ++rr2) {
                int row = rt * 4 + rr2;
                float4 dp = *(const float4*)(&s_dp[row][0]);
                short8v o;
                #pragma unroll
                for (int e = 0; e < 8; ++e) {
                    float4 wj = *(const float4*)(&s_w14[ct8 + e][0]);
                    float v = fmaf(dp.x, wj.x, fmaf(dp.y, wj.y, fmaf(dp.z, wj.z, wj.w)));
                    o[e] = (short)f2bf_rn(fmaxf(v, 0.f));
                }
                int off = (row * 256 + ct8 * 2) ^ ((row & 7) << 4);
                *(short8v*)((char*)s_t1 + off) = o;
            }
        }
        // stage qka = qa[col] - ka[row]
        {
            const int rq = t >> 2, q4 = t & 3;
            const unsigned short* qrow = qabf + (size_t)s_col[rq] * C;
            const unsigned short* krow = kabf + (size_t)s_row[rq] * C;
            #pragma unroll
            for (int i2 = 0; i2 < 4; ++i2) {
                int j0 = q4 * 32 + i2 * 8;
                ushort8v qa8 = *(const ushort8v*)(qrow + j0);
                ushort8v ka8 = *(const ushort8v*)(krow + j0);
                short8v o;
                #pragma unroll
                for (int e = 0; e < 8; ++e)
                    o[e] = (short)f2bf_rn(bf2f(qa8[e]) - bf2f(ka8[e]));
                int off = (rq * 256 + j0 * 2) ^ ((rq & 7) << 4);
                *(short8v*)((char*)s_qka + off) = o;
            }
        }
        __syncthreads();

        // GEMM: acc[mt][nt] holds pre[col = jw+nt*16+lg*4+r][edge = mt*16+ln15]
        f32x4 acc[4][2];
        const f32x4 zz = {0.f, 0.f, 0.f, 0.f};
        #pragma unroll
        for (int mt = 0; mt < 4; ++mt) { acc[mt][0] = zz; acc[mt][1] = zz; }
        #pragma unroll
        for (int mt = 0; mt < 4; ++mt) {
            int row = mt * 16 + ln15;
            #pragma unroll
            for (int ks = 0; ks < 4; ++ks) {
                int off = (row * 256 + (ks * 32 + lg * 8) * 2) ^ ((row & 7) << 4);
                frag16 b = *(const frag16*)((const char*)s_t1 + off);
                acc[mt][0] = MFMA16(aW[0][ks], b, acc[mt][0]);
                acc[mt][1] = MFMA16(aW[1][ks], b, acc[mt][1]);
            }
        }

        // epilogue: + qka + bias_c, relu, dot at_w2, reduce
        #pragma unroll
        for (int mt = 0; mt < 4; ++mt) {
            int edge = mt * 16 + ln15;
            float p = 0.f;
            #pragma unroll
            for (int nt = 0; nt < 2; ++nt) {
                int col0 = jw + nt * 16 + lg * 4;
                int off = (edge * 256 + col0 * 2) ^ ((edge & 7) << 4);
                ushort4 qk = *(const ushort4*)((const char*)s_qka + off);
                float t0 = fmaxf(acc[mt][nt][0] + bf2f(qk.x) + bcv[nt * 4 + 0], 0.f);
                float t1v = fmaxf(acc[mt][nt][1] + bf2f(qk.y) + bcv[nt * 4 + 1], 0.f);
                float t2v = fmaxf(acc[mt][nt][2] + bf2f(qk.z) + bcv[nt * 4 + 2], 0.f);
                float t3v = fmaxf(acc[mt][nt][3] + bf2f(qk.w) + bcv[nt * 4 + 3], 0.f);
                p = fmaf(t0, w2v[nt * 4 + 0], p);
                p = fmaf(t1v, w2v[nt * 4 + 1], p);
                p = fmaf(t2v, w2v[nt * 4 + 2], p);
                p = fmaf(t3v, w2v[nt * 4 + 3], p);
            }
            p += __shfl_xor(p, 16, 64);
            p += __shfl_xor(p, 32, 64);
            if (lane < 16) s_logit[edge][wv] = p;
        }
        __syncthreads();

        if (t < 64)
            logits[s0 + t] = s_logit[t][0] + s_logit[t][1]
                           + s_logit[t][2] + s_logit[t][3] + atb2;
    }
}

// ---------------- K4: per-node softmax + gather (v and t1 accumulation) -----
__global__ __launch_bounds__(256) void gather_kernel(
    const int* __restrict__ offsets, const int* __restrict__ rows_sorted,
    const float* __restrict__ dpos4, const float* __restrict__ logits,
    const unsigned short* __restrict__ vbf,
    const float* __restrict__ pm_w1, const float* __restrict__ pm_b1,
    float* __restrict__ out, unsigned short* __restrict__ ubf)
{
    int n = blockIdx.x * 2 + (threadIdx.x >> 7);
    int j = threadIdx.x & 127;
    if (n >= NN) return;
    int o0 = offsets[n], o1 = offsets[n + 1];

    float w1x = pm_w1[j], w1y = pm_w1[C + j], w1z = pm_w1[2 * C + j], b1 = pm_b1[j];

    float m = -1e30f;
    for (int i = o0; i < o1; ++i) m = fmaxf(m, logits[i]);
    float s = 0.0f;
    for (int i = o0; i < o1; ++i) s += __expf(logits[i] - m);
    float inv = (s > 0.0f) ? 1.0f / s : 0.0f;

    float accv = 0.0f, acct = 0.0f;
    for (int i = o0; i < o1; ++i) {
        float lw = __expf(logits[i] - m) * inv;
        int rv = rows_sorted[i];
        float4 dp = *(const float4*)(dpos4 + (size_t)i * 4);
        float t1 = fmaxf(fmaf(dp.x, w1x, fmaf(dp.y, w1y, fmaf(dp.z, w1z, b1))), 0.f);
        accv = fmaf(lw, bf2f(vbf[(size_t)rv * C + j]), accv);
        acct = fmaf(lw, t1, acct);
    }
    out[(size_t)n * C + j] += accv;
    ubf[(size_t)n * C + j] = f2bf_rn(acct);
}

// ---------------- K5: out += u @ pm_w2 + pm_b2 ----------------
__global__ __launch_bounds__(256, 4) void final_gemm(
    const unsigned short* __restrict__ ubf, const unsigned short* __restrict__ Wp2T,
    const float* __restrict__ pm_b2, float* __restrict__ out)
{
    __shared__ short s_u[64 * C];
    const int nb = blockIdx.x * 64;
    const int t = threadIdx.x;
    const int lane = t & 63, wv = t >> 6;
    const int ln15 = lane & 15, lg = lane >> 4;
    const int jw = wv * 32;

    {
        const int rq = t >> 2, q4 = t & 3;
        int row = nb + rq;
        #pragma unroll
        for (int i2 = 0; i2 < 4; ++i2) {
            int j0 = q4 * 32 + i2 * 8;
            short8v v = {0,0,0,0,0,0,0,0};
            if (row < NN) v = *(const short8v*)(ubf + (size_t)row * C + j0);
            int off = (rq * 256 + j0 * 2) ^ ((rq & 7) << 4);
            *(short8v*)((char*)s_u + off) = v;
        }
    }
    __syncthreads();

    frag16 aW[2][4];
    #pragma unroll
    for (int nt = 0; nt < 2; ++nt)
        #pragma unroll
        for (int ks = 0; ks < 4; ++ks)
            aW[nt][ks] = *(const frag16*)(Wp2T + (size_t)(jw + nt * 16 + ln15) * C
                                             + ks * 32 + lg * 8);
    f32x4 acc[4][2];
    const f32x4 zz = {0.f, 0.f, 0.f, 0.f};
    #pragma unroll
    for (int mt = 0; mt < 4; ++mt) { acc[mt][0] = zz; acc[mt][1] = zz; }

    #pragma unroll
    for (int mt = 0; mt < 4; ++mt) {
        int row = mt * 16 + ln15;
        #pragma unroll
        for (int ks = 0; ks < 4; ++ks) {
            int off = (row * 256 + (ks * 32 + lg * 8) * 2) ^ ((row & 7) << 4);
            frag16 b = *(const frag16*)((const char*)s_u + off);
            acc[mt][0] = MFMA16(aW[0][ks], b, acc[mt][0]);
            acc[mt][1] = MFMA16(aW[1][ks], b, acc[mt][1]);
        }
    }

    #pragma unroll
    for (int nt = 0; nt < 2; ++nt) {
        int col0 = jw + nt * 16 + lg * 4;
        float4 b2 = *(const float4*)(pm_b2 + col0);
        #pragma unroll
        for (int mt = 0; mt < 4; ++mt) {
            int node = nb + mt * 16 + ln15;
            if (node < NN) {
                float4 o = *(float4*)(out + (size_t)node * C + col0);
                o.x += acc[mt][nt][0] + b2.x; o.y += acc[mt][nt][1] + b2.y;
                o.z += acc[mt][nt][2] + b2.z; o.w += acc[mt][nt][3] + b2.w;
                *(float4*)(out + (size_t)node * C + col0) = o;
            }
        }
    }
}

// ---------------- launch ----------------
extern "C" void kernel_launch(void* const* d_in, const int* in_sizes, int n_in,
                              void* d_out, int out_size, void* d_ws, size_t ws_size,
                              hipStream_t stream)
{
    (void)in_sizes; (void)n_in; (void)out_size; (void)ws_size;
    const float* x      = (const float*)d_in[0];
    const float* pos    = (const float*)d_in[1];
    const int*   eidx   = (const int*)d_in[2];
    const float* Wq     = (const float*)d_in[3];
    const float* Wk     = (const float*)d_in[4];
    const float* Wv     = (const float*)d_in[5];
    const float* pm_w1  = (const float*)d_in[6];
    const float* pm_b1  = (const float*)d_in[7];
    const float* pm_w2  = (const float*)d_in[8];
    const float* pm_b2  = (const float*)d_in[9];
    const float* at_w1  = (const float*)d_in[10];
    const float* at_b1  = (const float*)d_in[11];
    const float* at_w2  = (const float*)d_in[12];
    const float* at_b2  = (const float*)d_in[13];
    const float* root_w = (const float*)d_in[14];
    const float* root_b = (const float*)d_in[15];
    float* out = (float*)d_out;

    char* w = (char*)d_ws;
    unsigned short* xbf  = (unsigned short*)w; w += (size_t)NN * C * 2;
    unsigned short* vbf  = (unsigned short*)w; w += (size_t)NN * C * 2;
    unsigned short* qabf = (unsigned short*)w; w += (size_t)NN * C * 2;
    unsigned short* kabf = (unsigned short*)w; w += (size_t)NN * C * 2;
    unsigned short* ubf  = (unsigned short*)w; w += (size_t)NN * C * 2;
    float* logits        = (float*)w; w += (size_t)EE * 4;
    float* dpos4         = (float*)w; w += (size_t)EE * 16;
    unsigned short* WcT  = (unsigned short*)w; w += (size_t)C * C * 2;
    unsigned short* WqaT = (unsigned short*)w; w += (size_t)C * C * 2;
    unsigned short* WkaT = (unsigned short*)w; w += (size_t)C * C * 2;
    unsigned short* WvT  = (unsigned short*)w; w += (size_t)C * C * 2;
    unsigned short* WrT  = (unsigned short*)w; w += (size_t)C * C * 2;
    unsigned short* Wp2T = (unsigned short*)w; w += (size_t)C * C * 2;
    float* bias_c        = (float*)w; w += 512;
    int* rows_sorted = (int*)w; w += (size_t)EE * 4;
    int* cols_sorted = (int*)w; w += (size_t)EE * 4;
    int* counts      = (int*)w; w += (size_t)NN * 4;
    int* cursor      = (int*)w; w += (size_t)NN * 4;
    int* offsets     = (int*)w; w += (size_t)(NN + 1) * 4;

    hipMemsetAsync(counts, 0, (size_t)NN * 4, stream);
    hipMemsetAsync(cursor, 0, (size_t)NN * 4, stream);

    convert_kernel<<<(NN * C / 4 + 255) / 256, 256, 0, stream>>>(x, xbf);

    prep_kernel<<<dim3(64, 7), 256, 0, stream>>>(
        pm_w2, at_w1, Wq, Wk, Wv, root_w, pm_b2, at_b1,
        WcT, WqaT, WkaT, WvT, WrT, Wp2T, bias_c);

    hist_kernel<<<(EE + 255) / 256, 256, 0, stream>>>(eidx, counts);
    scan_kernel<<<1, 1024, 0, stream>>>(counts, offsets, NN);
    fill_kernel<<<(EE + 255) / 256, 256, 0, stream>>>(
        eidx, pos, offsets, cursor, rows_sorted, cols_sorted, dpos4);

    node_gemm<<<(NN + 63) / 64, 256, 0, stream>>>(
        xbf, WvT, WqaT, WkaT, WrT, root_b, vbf, qabf, kabf, out);

    edge_kernel<<<EGRID, 256, 0, stream>>>(
        rows_sorted, cols_sorted, dpos4, qabf, kabf,
        pm_w1, pm_b1, WcT, bias_c, at_w2, at_b2, logits);

    gather_kernel<<<(NN + 1) / 2, 256, 0, stream>>>(
        offsets, rows_sorted, dpos4, logits, vbf, pm_w1, pm_b1, out, ubf);

    final_gemm<<<(NN + 63) / 64, 256, 0, stream>>>(ubf, Wp2T, pm_b2, out);
}

// Round 4
// 360.903 us; speedup vs baseline: 2.5408x; 1.3215x over previous
//
#include <hip/hip_runtime.h>
#include <hip/hip_bf16.h>

#define NN 30000
#define EE 480000
#define C  128
#define NTILES (EE / 64)   // 7500
#define EGRID 2500

typedef __attribute__((ext_vector_type(8))) short          short8v;
typedef __attribute__((ext_vector_type(8))) unsigned short ushort8v;
typedef __attribute__((ext_vector_type(8))) short          frag16;   // 8 bf16
typedef __attribute__((ext_vector_type(4))) float          f32x4;

#define MFMA16(a, b, c) __builtin_amdgcn_mfma_f32_16x16x32_bf16(a, b, c, 0, 0, 0)

static __device__ __forceinline__ unsigned short f2bf_rn(float f) {
    unsigned int u = __float_as_uint(f);
    unsigned int r = (u + 0x7fffu + ((u >> 16) & 1u)) >> 16;
    return (unsigned short)r;
}
static __device__ __forceinline__ float bf2f(unsigned short s) {
    return __uint_as_float(((unsigned int)s) << 16);
}

// ---------------- P0: weight precomputes (all outputs TRANSPOSED bf16) ------
__global__ __launch_bounds__(256) void prep_kernel(
    const float* __restrict__ pm_w2, const float* __restrict__ at_w1,
    const float* __restrict__ Wq, const float* __restrict__ Wk,
    const float* __restrict__ Wv, const float* __restrict__ root_w,
    const float* __restrict__ pm_b2, const float* __restrict__ at_b1,
    unsigned short* __restrict__ WcT, unsigned short* __restrict__ WqaT,
    unsigned short* __restrict__ WkaT, unsigned short* __restrict__ WvT,
    unsigned short* __restrict__ WrT, unsigned short* __restrict__ Wp2T,
    float* __restrict__ bias_c)
{
    const int which = blockIdx.y;
    const int t = threadIdx.x;
    const int i = blockIdx.x * 2 + (t >> 7), j = t & 127;

    if (which == 3) {
        if (blockIdx.x == 0 && t < C) {
            float s = at_b1[t];
            for (int k = 0; k < C; ++k) s = fmaf(pm_b2[k], at_w1[k * C + t], s);
            bias_c[t] = s;
        }
        return;
    }
    if (which >= 4) {
        const float* A = (which == 4) ? Wv : (which == 5) ? root_w : pm_w2;
        unsigned short* OT = (which == 4) ? WvT : (which == 5) ? WrT : Wp2T;
        OT[j * C + i] = f2bf_rn(A[i * C + j]);
        return;
    }
    const float* A = (which == 0) ? pm_w2 : (which == 1) ? Wq : Wk;
    unsigned short* OT = (which == 0) ? WcT : (which == 1) ? WqaT : WkaT;

    __shared__ float sA[2][C];
    sA[t >> 7][j] = A[i * C + j];
    __syncthreads();
    float s = 0.f;
    for (int k = 0; k < C; ++k) s = fmaf(sA[t >> 7][k], at_w1[k * C + j], s);
    OT[j * C + i] = f2bf_rn(s);
}

// ---------------- x -> bf16 ----------------
__global__ __launch_bounds__(256) void convert_kernel(const float* __restrict__ x,
                                                      unsigned short* __restrict__ xbf)
{
    int i = (blockIdx.x * 256 + threadIdx.x) * 4;
    if (i < NN * C) {
        float4 v = *(const float4*)(x + i);
        ushort4 u;
        u.x = f2bf_rn(v.x); u.y = f2bf_rn(v.y); u.z = f2bf_rn(v.z); u.w = f2bf_rn(v.w);
        *(ushort4*)(xbf + i) = u;
    }
}

// ---------------- K1: node GEMMs via MFMA (swapped operands) ----------------
__global__ __launch_bounds__(256, 4) void node_gemm(
    const unsigned short* __restrict__ xbf,
    const unsigned short* __restrict__ WvT, const unsigned short* __restrict__ WqaT,
    const unsigned short* __restrict__ WkaT, const unsigned short* __restrict__ WrT,
    const float* __restrict__ root_b,
    unsigned short* __restrict__ vbf, unsigned short* __restrict__ qabf,
    unsigned short* __restrict__ kabf, float* __restrict__ out)
{
    __shared__ short s_x[64 * C];   // bf16, swizzled
    const int nb = blockIdx.x * 64;
    const int t = threadIdx.x;
    const int lane = t & 63, wv = t >> 6;
    const int ln15 = lane & 15, lg = lane >> 4;
    const int jw = wv * 32;

    {   // stage x tile
        const int rq = t >> 2, q4 = t & 3;
        int row = nb + rq;
        #pragma unroll
        for (int i2 = 0; i2 < 4; ++i2) {
            int j0 = q4 * 32 + i2 * 8;
            short8v v = {0,0,0,0,0,0,0,0};
            if (row < NN) v = *(const short8v*)(xbf + (size_t)row * C + j0);
            int off = (rq * 256 + j0 * 2) ^ ((rq & 7) << 4);
            *(short8v*)((char*)s_x + off) = v;
        }
    }
    __syncthreads();

    for (int m = 0; m < 4; ++m) {
        const unsigned short* WT;
        switch (m) {
            case 0: WT = WvT;  break; case 1: WT = WqaT; break;
            case 2: WT = WkaT; break; default: WT = WrT;
        }
        frag16 aW[2][4];
        #pragma unroll
        for (int nt = 0; nt < 2; ++nt)
            #pragma unroll
            for (int ks = 0; ks < 4; ++ks)
                aW[nt][ks] = *(const frag16*)(WT + (size_t)(jw + nt * 16 + ln15) * C
                                                 + ks * 32 + lg * 8);
        f32x4 acc[4][2];
        const f32x4 zz = {0.f, 0.f, 0.f, 0.f};
        #pragma unroll
        for (int mt = 0; mt < 4; ++mt) { acc[mt][0] = zz; acc[mt][1] = zz; }

        #pragma unroll
        for (int mt = 0; mt < 4; ++mt) {
            int row = mt * 16 + ln15;
            #pragma unroll
            for (int ks = 0; ks < 4; ++ks) {
                int off = (row * 256 + (ks * 32 + lg * 8) * 2) ^ ((row & 7) << 4);
                frag16 b = *(const frag16*)((const char*)s_x + off);
                acc[mt][0] = MFMA16(aW[0][ks], b, acc[mt][0]);
                acc[mt][1] = MFMA16(aW[1][ks], b, acc[mt][1]);
            }
        }

        if (m == 3) {
            #pragma unroll
            for (int nt = 0; nt < 2; ++nt) {
                int col0 = jw + nt * 16 + lg * 4;
                float4 rb = *(const float4*)(root_b + col0);
                #pragma unroll
                for (int mt = 0; mt < 4; ++mt) {
                    int node = nb + mt * 16 + ln15;
                    if (node < NN) {
                        float4 o;
                        o.x = acc[mt][nt][0] + rb.x; o.y = acc[mt][nt][1] + rb.y;
                        o.z = acc[mt][nt][2] + rb.z; o.w = acc[mt][nt][3] + rb.w;
                        *(float4*)(out + (size_t)node * C + col0) = o;
                    }
                }
            }
        } else {
            unsigned short* OB = (m == 0) ? vbf : (m == 1) ? qabf : kabf;
            #pragma unroll
            for (int nt = 0; nt < 2; ++nt) {
                int col0 = jw + nt * 16 + lg * 4;
                #pragma unroll
                for (int mt = 0; mt < 4; ++mt) {
                    int node = nb + mt * 16 + ln15;
                    if (node < NN) {
                        ushort4 u;
                        u.x = f2bf_rn(acc[mt][nt][0]); u.y = f2bf_rn(acc[mt][nt][1]);
                        u.z = f2bf_rn(acc[mt][nt][2]); u.w = f2bf_rn(acc[mt][nt][3]);
                        *(ushort4*)(OB + (size_t)node * C + col0) = u;
                    }
                }
            }
        }
    }
}

// ---------------- K3: CSR build by destination ----------------
__global__ __launch_bounds__(256) void hist_kernel(const int* __restrict__ eidx,
                                                   int* __restrict__ counts)
{
    int e = blockIdx.x * 256 + threadIdx.x;
    if (e < EE) atomicAdd(&counts[eidx[EE + e]], 1);
}

__global__ __launch_bounds__(1024) void scan_kernel(const int* __restrict__ counts,
                                                    int* __restrict__ offsets, int n)
{
    __shared__ int wsum[16];
    __shared__ int wpre[16];
    __shared__ int tot_s;
    int t = threadIdx.x;
    int lane = t & 63, w = t >> 6;
    int carry = 0;
    for (int base = 0; base < n; base += 1024) {
        int i = base + t;
        int v = (i < n) ? counts[i] : 0;
        int incl = v;
        #pragma unroll
        for (int d = 1; d < 64; d <<= 1) {
            int u = __shfl_up(incl, d, 64);
            if (lane >= d) incl += u;
        }
        if (lane == 63) wsum[w] = incl;
        __syncthreads();
        if (t == 0) {
            int run = 0;
            #pragma unroll
            for (int ww = 0; ww < 16; ++ww) { wpre[ww] = run; run += wsum[ww]; }
            tot_s = run;
        }
        __syncthreads();
        if (i < n) offsets[i] = carry + wpre[w] + incl - v;
        carry += tot_s;
        __syncthreads();
    }
    if (t == 0) offsets[n] = carry;
}

__global__ __launch_bounds__(256) void fill_kernel(const int* __restrict__ eidx,
                                                   const float* __restrict__ pos,
                                                   const int* __restrict__ offsets,
                                                   int* __restrict__ cursor,
                                                   int* __restrict__ rows_sorted,
                                                   int* __restrict__ cols_sorted,
                                                   float* __restrict__ dpos4)
{
    int e = blockIdx.x * 256 + threadIdx.x;
    if (e < EE) {
        int r = eidx[e];
        int c = eidx[EE + e];
        int p = atomicAdd(&cursor[c], 1);
        int slot = offsets[c] + p;
        rows_sorted[slot] = r;
        cols_sorted[slot] = c;
        float4 d;
        d.x = pos[r * 3 + 0] - pos[c * 3 + 0];
        d.y = pos[r * 3 + 1] - pos[c * 3 + 1];
        d.z = pos[r * 3 + 2] - pos[c * 3 + 2];
        d.w = 0.f;
        *(float4*)(dpos4 + (size_t)slot * 4) = d;
    }
}

// ---------------- K2: per-edge logits via MFMA (swapped) ----------------
__global__ __launch_bounds__(256, 4) void edge_kernel(
    const int* __restrict__ rows_sorted, const int* __restrict__ cols_sorted,
    const float* __restrict__ dpos4,
    const unsigned short* __restrict__ qabf, const unsigned short* __restrict__ kabf,
    const float* __restrict__ pm_w1, const float* __restrict__ pm_b1,
    const unsigned short* __restrict__ WcT, const float* __restrict__ bias_c,
    const float* __restrict__ at_w2, const float* __restrict__ at_b2,
    float* __restrict__ logits)
{
    __shared__ short s_t1[64 * C];    // bf16, swizzled
    __shared__ short s_qka[64 * C];   // bf16, swizzled
    __shared__ float s_dp[64][4];
    __shared__ int   s_row[64], s_col[64];
    __shared__ float s_logit[64][4];

    const int t = threadIdx.x;
    const int lane = t & 63, wv = t >> 6;
    const int ln15 = lane & 15, lg = lane >> 4;
    const int jw = wv * 32;

    // w14 in REGISTERS (was LDS: 16-way bank conflict — 6.1e7 cycles)
    const int rt = t >> 4, ct8 = (t & 15) * 8;
    float w1xr[8], w1yr[8], w1zr[8], w1br[8];
    #pragma unroll
    for (int e = 0; e < 8; ++e) {
        int j = ct8 + e;
        w1xr[e] = pm_w1[j];
        w1yr[e] = pm_w1[C + j];
        w1zr[e] = pm_w1[2 * C + j];
        w1br[e] = pm_b1[j];
    }

    // per-lane constants: cols jw + nt*16 + lg*4 + r
    float bcv[8], w2v[8];
    #pragma unroll
    for (int nt = 0; nt < 2; ++nt) {
        int col0 = jw + nt * 16 + lg * 4;
        float4 b4 = *(const float4*)(bias_c + col0);
        float4 w4 = *(const float4*)(at_w2 + col0);
        bcv[nt * 4 + 0] = b4.x; bcv[nt * 4 + 1] = b4.y;
        bcv[nt * 4 + 2] = b4.z; bcv[nt * 4 + 3] = b4.w;
        w2v[nt * 4 + 0] = w4.x; w2v[nt * 4 + 1] = w4.y;
        w2v[nt * 4 + 2] = w4.z; w2v[nt * 4 + 3] = w4.w;
    }
    const float atb2 = at_b2[0];

    frag16 aW[2][4];
    #pragma unroll
    for (int nt = 0; nt < 2; ++nt)
        #pragma unroll
        for (int ks = 0; ks < 4; ++ks)
            aW[nt][ks] = *(const frag16*)(WcT + (size_t)(jw + nt * 16 + ln15) * C
                                             + ks * 32 + lg * 8);

    for (int tile = blockIdx.x; tile < NTILES; tile += EGRID) {
        const int s0 = tile * 64;

        __syncthreads();
        if (t < 64) {
            s_row[t] = rows_sorted[s0 + t];
            s_col[t] = cols_sorted[s0 + t];
            *(float4*)(&s_dp[t][0]) = *(const float4*)(dpos4 + (size_t)(s0 + t) * 4);
        }
        __syncthreads();

        // stage t1 = relu(dpos@pm_w1 + pm_b1), bf16 swizzled
        #pragma unroll
        for (int rr2 = 0; rr2 < 4; ++rr2) {
            int row = rt * 4 + rr2;
            float4 dp = *(const float4*)(&s_dp[row][0]);   // broadcast read
            short8v o;
            #pragma unroll
            for (int e = 0; e < 8; ++e) {
                float v = fmaf(dp.x, w1xr[e], fmaf(dp.y, w1yr[e], fmaf(dp.z, w1zr[e], w1br[e])));
                o[e] = (short)f2bf_rn(fmaxf(v, 0.f));
            }
            int off = (row * 256 + ct8 * 2) ^ ((row & 7) << 4);
            *(short8v*)((char*)s_t1 + off) = o;
        }
        // stage qka = qa[col] - ka[row]
        {
            const int rq = t >> 2, q4 = t & 3;
            const unsigned short* qrow = qabf + (size_t)s_col[rq] * C;
            const unsigned short* krow = kabf + (size_t)s_row[rq] * C;
            #pragma unroll
            for (int i2 = 0; i2 < 4; ++i2) {
                int j0 = q4 * 32 + i2 * 8;
                ushort8v qa8 = *(const ushort8v*)(qrow + j0);
                ushort8v ka8 = *(const ushort8v*)(krow + j0);
                short8v o;
                #pragma unroll
                for (int e = 0; e < 8; ++e)
                    o[e] = (short)f2bf_rn(bf2f(qa8[e]) - bf2f(ka8[e]));
                int off = (rq * 256 + j0 * 2) ^ ((rq & 7) << 4);
                *(short8v*)((char*)s_qka + off) = o;
            }
        }
        __syncthreads();

        // GEMM: acc[mt][nt] holds pre[col = jw+nt*16+lg*4+r][edge = mt*16+ln15]
        f32x4 acc[4][2];
        const f32x4 zz = {0.f, 0.f, 0.f, 0.f};
        #pragma unroll
        for (int mt = 0; mt < 4; ++mt) { acc[mt][0] = zz; acc[mt][1] = zz; }
        #pragma unroll
        for (int mt = 0; mt < 4; ++mt) {
            int row = mt * 16 + ln15;
            #pragma unroll
            for (int ks = 0; ks < 4; ++ks) {
                int off = (row * 256 + (ks * 32 + lg * 8) * 2) ^ ((row & 7) << 4);
                frag16 b = *(const frag16*)((const char*)s_t1 + off);
                acc[mt][0] = MFMA16(aW[0][ks], b, acc[mt][0]);
                acc[mt][1] = MFMA16(aW[1][ks], b, acc[mt][1]);
            }
        }

        // epilogue: + qka + bias_c, relu, dot at_w2, reduce
        #pragma unroll
        for (int mt = 0; mt < 4; ++mt) {
            int edge = mt * 16 + ln15;
            float p = 0.f;
            #pragma unroll
            for (int nt = 0; nt < 2; ++nt) {
                int col0 = jw + nt * 16 + lg * 4;
                int off = (edge * 256 + col0 * 2) ^ ((edge & 7) << 4);
                ushort4 qk = *(const ushort4*)((const char*)s_qka + off);
                float t0 = fmaxf(acc[mt][nt][0] + bf2f(qk.x) + bcv[nt * 4 + 0], 0.f);
                float t1v = fmaxf(acc[mt][nt][1] + bf2f(qk.y) + bcv[nt * 4 + 1], 0.f);
                float t2v = fmaxf(acc[mt][nt][2] + bf2f(qk.z) + bcv[nt * 4 + 2], 0.f);
                float t3v = fmaxf(acc[mt][nt][3] + bf2f(qk.w) + bcv[nt * 4 + 3], 0.f);
                p = fmaf(t0, w2v[nt * 4 + 0], p);
                p = fmaf(t1v, w2v[nt * 4 + 1], p);
                p = fmaf(t2v, w2v[nt * 4 + 2], p);
                p = fmaf(t3v, w2v[nt * 4 + 3], p);
            }
            p += __shfl_xor(p, 16, 64);
            p += __shfl_xor(p, 32, 64);
            if (lane < 16) s_logit[edge][wv] = p;
        }
        __syncthreads();

        if (t < 64)
            logits[s0 + t] = s_logit[t][0] + s_logit[t][1]
                           + s_logit[t][2] + s_logit[t][3] + atb2;
    }
}

// ---------------- K3b: softmax weights (one wave per node) ----------------
__global__ __launch_bounds__(256) void weights_kernel(
    const int* __restrict__ offsets, const float* __restrict__ logits,
    float* __restrict__ wts)
{
    int n = blockIdx.x * 4 + (threadIdx.x >> 6);
    if (n >= NN) return;
    int lane = threadIdx.x & 63;
    int o0 = offsets[n], o1 = offsets[n + 1];

    float m = -1e30f;
    for (int i = o0 + lane; i < o1; i += 64) m = fmaxf(m, logits[i]);
    #pragma unroll
    for (int d = 1; d < 64; d <<= 1) m = fmaxf(m, __shfl_xor(m, d, 64));
    float s = 0.f;
    for (int i = o0 + lane; i < o1; i += 64) s += __expf(logits[i] - m);
    #pragma unroll
    for (int d = 1; d < 64; d <<= 1) s += __shfl_xor(s, d, 64);
    float inv = (s > 0.f) ? 1.f / s : 0.f;
    for (int i = o0 + lane; i < o1; i += 64) wts[i] = __expf(logits[i] - m) * inv;
}

// ---------------- K4: per-node gather (v and t1 accumulation) -----
__global__ __launch_bounds__(256) void gather_kernel(
    const int* __restrict__ offsets, const int* __restrict__ rows_sorted,
    const float* __restrict__ dpos4, const float* __restrict__ wts,
    const unsigned short* __restrict__ vbf,
    const float* __restrict__ pm_w1, const float* __restrict__ pm_b1,
    float* __restrict__ out, unsigned short* __restrict__ ubf)
{
    int n = blockIdx.x * 2 + (threadIdx.x >> 7);
    int j = threadIdx.x & 127;
    if (n >= NN) return;
    int o0 = offsets[n], o1 = offsets[n + 1];

    float w1x = pm_w1[j], w1y = pm_w1[C + j], w1z = pm_w1[2 * C + j], b1 = pm_b1[j];

    float accv = 0.0f, acct = 0.0f;
    for (int i = o0; i < o1; ++i) {
        float lw = wts[i];
        int rv = rows_sorted[i];
        float4 dp = *(const float4*)(dpos4 + (size_t)i * 4);
        float t1 = fmaxf(fmaf(dp.x, w1x, fmaf(dp.y, w1y, fmaf(dp.z, w1z, b1))), 0.f);
        accv = fmaf(lw, bf2f(vbf[(size_t)rv * C + j]), accv);
        acct = fmaf(lw, t1, acct);
    }
    out[(size_t)n * C + j] += accv;
    ubf[(size_t)n * C + j] = f2bf_rn(acct);
}

// ---------------- K5: out += u @ pm_w2 + pm_b2 ----------------
__global__ __launch_bounds__(256, 4) void final_gemm(
    const unsigned short* __restrict__ ubf, const unsigned short* __restrict__ Wp2T,
    const float* __restrict__ pm_b2, float* __restrict__ out)
{
    __shared__ short s_u[64 * C];
    const int nb = blockIdx.x * 64;
    const int t = threadIdx.x;
    const int lane = t & 63, wv = t >> 6;
    const int ln15 = lane & 15, lg = lane >> 4;
    const int jw = wv * 32;

    {
        const int rq = t >> 2, q4 = t & 3;
        int row = nb + rq;
        #pragma unroll
        for (int i2 = 0; i2 < 4; ++i2) {
            int j0 = q4 * 32 + i2 * 8;
            short8v v = {0,0,0,0,0,0,0,0};
            if (row < NN) v = *(const short8v*)(ubf + (size_t)row * C + j0);
            int off = (rq * 256 + j0 * 2) ^ ((rq & 7) << 4);
            *(short8v*)((char*)s_u + off) = v;
        }
    }
    __syncthreads();

    frag16 aW[2][4];
    #pragma unroll
    for (int nt = 0; nt < 2; ++nt)
        #pragma unroll
        for (int ks = 0; ks < 4; ++ks)
            aW[nt][ks] = *(const frag16*)(Wp2T + (size_t)(jw + nt * 16 + ln15) * C
                                             + ks * 32 + lg * 8);
    f32x4 acc[4][2];
    const f32x4 zz = {0.f, 0.f, 0.f, 0.f};
    #pragma unroll
    for (int mt = 0; mt < 4; ++mt) { acc[mt][0] = zz; acc[mt][1] = zz; }

    #pragma unroll
    for (int mt = 0; mt < 4; ++mt) {
        int row = mt * 16 + ln15;
        #pragma unroll
        for (int ks = 0; ks < 4; ++ks) {
            int off = (row * 256 + (ks * 32 + lg * 8) * 2) ^ ((row & 7) << 4);
            frag16 b = *(const frag16*)((const char*)s_u + off);
            acc[mt][0] = MFMA16(aW[0][ks], b, acc[mt][0]);
            acc[mt][1] = MFMA16(aW[1][ks], b, acc[mt][1]);
        }
    }

    #pragma unroll
    for (int nt = 0; nt < 2; ++nt) {
        int col0 = jw + nt * 16 + lg * 4;
        float4 b2 = *(const float4*)(pm_b2 + col0);
        #pragma unroll
        for (int mt = 0; mt < 4; ++mt) {
            int node = nb + mt * 16 + ln15;
            if (node < NN) {
                float4 o = *(float4*)(out + (size_t)node * C + col0);
                o.x += acc[mt][nt][0] + b2.x; o.y += acc[mt][nt][1] + b2.y;
                o.z += acc[mt][nt][2] + b2.z; o.w += acc[mt][nt][3] + b2.w;
                *(float4*)(out + (size_t)node * C + col0) = o;
            }
        }
    }
}

// ---------------- launch ----------------
extern "C" void kernel_launch(void* const* d_in, const int* in_sizes, int n_in,
                              void* d_out, int out_size, void* d_ws, size_t ws_size,
                              hipStream_t stream)
{
    (void)in_sizes; (void)n_in; (void)out_size; (void)ws_size;
    const float* x      = (const float*)d_in[0];
    const float* pos    = (const float*)d_in[1];
    const int*   eidx   = (const int*)d_in[2];
    const float* Wq     = (const float*)d_in[3];
    const float* Wk     = (const float*)d_in[4];
    const float* Wv     = (const float*)d_in[5];
    const float* pm_w1  = (const float*)d_in[6];
    const float* pm_b1  = (const float*)d_in[7];
    const float* pm_w2  = (const float*)d_in[8];
    const float* pm_b2  = (const float*)d_in[9];
    const float* at_w1  = (const float*)d_in[10];
    const float* at_b1  = (const float*)d_in[11];
    const float* at_w2  = (const float*)d_in[12];
    const float* at_b2  = (const float*)d_in[13];
    const float* root_w = (const float*)d_in[14];
    const float* root_b = (const float*)d_in[15];
    float* out = (float*)d_out;

    char* w = (char*)d_ws;
    unsigned short* xbf  = (unsigned short*)w; w += (size_t)NN * C * 2;
    unsigned short* vbf  = (unsigned short*)w; w += (size_t)NN * C * 2;
    unsigned short* qabf = (unsigned short*)w; w += (size_t)NN * C * 2;
    unsigned short* kabf = (unsigned short*)w; w += (size_t)NN * C * 2;
    unsigned short* ubf  = (unsigned short*)w; w += (size_t)NN * C * 2;
    float* logits        = (float*)w; w += (size_t)EE * 4;
    float* wts           = (float*)w; w += (size_t)EE * 4;
    float* dpos4         = (float*)w; w += (size_t)EE * 16;
    unsigned short* WcT  = (unsigned short*)w; w += (size_t)C * C * 2;
    unsigned short* WqaT = (unsigned short*)w; w += (size_t)C * C * 2;
    unsigned short* WkaT = (unsigned short*)w; w += (size_t)C * C * 2;
    unsigned short* WvT  = (unsigned short*)w; w += (size_t)C * C * 2;
    unsigned short* WrT  = (unsigned short*)w; w += (size_t)C * C * 2;
    unsigned short* Wp2T = (unsigned short*)w; w += (size_t)C * C * 2;
    float* bias_c        = (float*)w; w += 512;
    int* rows_sorted = (int*)w; w += (size_t)EE * 4;
    int* cols_sorted = (int*)w; w += (size_t)EE * 4;
    int* counts      = (int*)w; w += (size_t)NN * 4;
    int* cursor      = (int*)w; w += (size_t)NN * 4;
    int* offsets     = (int*)w; w += (size_t)(NN + 1) * 4;

    hipMemsetAsync(counts, 0, (size_t)NN * 4, stream);
    hipMemsetAsync(cursor, 0, (size_t)NN * 4, stream);

    convert_kernel<<<(NN * C / 4 + 255) / 256, 256, 0, stream>>>(x, xbf);

    prep_kernel<<<dim3(64, 7), 256, 0, stream>>>(
        pm_w2, at_w1, Wq, Wk, Wv, root_w, pm_b2, at_b1,
        WcT, WqaT, WkaT, WvT, WrT, Wp2T, bias_c);

    hist_kernel<<<(EE + 255) / 256, 256, 0, stream>>>(eidx, counts);
    scan_kernel<<<1, 1024, 0, stream>>>(counts, offsets, NN);
    fill_kernel<<<(EE + 255) / 256, 256, 0, stream>>>(
        eidx, pos, offsets, cursor, rows_sorted, cols_sorted, dpos4);

    node_gemm<<<(NN + 63) / 64, 256, 0, stream>>>(
        xbf, WvT, WqaT, WkaT, WrT, root_b, vbf, qabf, kabf, out);

    edge_kernel<<<EGRID, 256, 0, stream>>>(
        rows_sorted, cols_sorted, dpos4, qabf, kabf,
        pm_w1, pm_b1, WcT, bias_c, at_w2, at_b2, logits);

    weights_kernel<<<(NN + 3) / 4, 256, 0, stream>>>(offsets, logits, wts);

    gather_kernel<<<(NN + 1) / 2, 256, 0, stream>>>(
        offsets, rows_sorted, dpos4, wts, vbf, pm_w1, pm_b1, out, ubf);

    final_gemm<<<(NN + 63) / 64, 256, 0, stream>>>(ubf, Wp2T, pm_b2, out);
}